// Round 11
// baseline (60.525 us; speedup 1.0000x reference)
//
#include <hip/hip_runtime.h>

#define DIM 1024
#define ROWS_PER_TILE 16

typedef float  f32x4  __attribute__((ext_vector_type(4)));
typedef short  bf16x8 __attribute__((ext_vector_type(8)));
typedef unsigned int u32x2 __attribute__((ext_vector_type(2)));

#define WF_BYTES (2 * 32 * 2 * 64 * 16)   // wf1 (64KB) + wf2 (64KB) = 128KB in d_ws

// ===========================================================================
// Reformulation: y = x * M, M = S0*S1*...*S9 (row-vector convention).
// Stages 0-4 mix bits 0-4 only  -> C1 = blockdiag over contiguous 32-groups g:
//   z[r][g*32+n] = sum_k x[r][g*32+k] * A_g[k][n]
// Stages 5-9 mix bits 5-9 only  -> C2 = blockdiag over stride-32 groups t:
//   y[r][n*32+t] = sum_k z[r][k*32+t] * B_t[k][n]
// A_g uses Ws[i][g*16+pl] (i=0..4); B_t uses Ws[5+il][pl*32+t] (il=0..4).
// MFMA 16x16x32 bf16. k-order per lane: k = (lane>>4)*8 + e, consistently for
// A and B operands (any consistent k-permutation gives the same contraction).
// C/D layout (HW-verified): col = lane&15, row = (lane>>4)*4 + i.
// ===========================================================================

__device__ __forceinline__ short f2bfs(float f) {
    union { __bf16 b; short s; } c; c.b = (__bf16)f; return c.s;
}
__device__ __forceinline__ unsigned f2bfbits(float f) {
    union { __bf16 b; unsigned short u; } c; c.b = (__bf16)f; return (unsigned)c.u;
}

// ---- compose A_g / B_t from Ws and emit B-operand fragments (bf16) ----------
// block b<32: A_{g=b} -> wf[0..64KB); b>=32: B_{t=b-32} -> wf[64KB..128KB)
__global__ __launch_bounds__(64) void compose_pack(const float* __restrict__ Ws,
                                                   short* __restrict__ wf) {
    __shared__ float M[32 * 32];
    const int b = blockIdx.x;
    const int tid = threadIdx.x;
    const bool isB = b >= 32;
    const int grp = isB ? b - 32 : b;

    for (int s = tid; s < 1024; s += 64) M[s] = ((s >> 5) == (s & 31)) ? 1.f : 0.f;
    __syncthreads();

    for (int il = 0; il < 5; ++il) {
        #pragma unroll
        for (int s = 0; s < 8; ++s) {
            int task = tid + s * 64;        // 512 tasks: pl(16) x row(32), disjoint
            int pl = task >> 5;
            int r  = task & 31;
            int lo = ((pl >> il) << (il + 1)) | (pl & ((1 << il) - 1));
            int hi = lo + (1 << il);
            int wi = isB ? ((5 + il) * 512 + pl * 32 + grp)
                         : (il * 512 + grp * 16 + pl);
            const float* W = Ws + (size_t)wi * 4;
            float w00 = W[0], w01 = W[1], w10 = W[2], w11 = W[3];
            float u = M[r * 32 + lo], v = M[r * 32 + hi];
            M[r * 32 + lo] = u * w00 + v * w10;   // new col lo
            M[r * 32 + hi] = u * w01 + v * w11;   // new col hi
        }
        __syncthreads();
    }

    // emit B-fragment: lane tid supplies B[k=(tid>>4)*8+e][n=nh*16+(tid&15)]
    const int q = tid >> 4, lr = tid & 15;
    #pragma unroll
    for (int nh = 0; nh < 2; ++nh) {
        bf16x8 fr;
        #pragma unroll
        for (int e = 0; e < 8; ++e)
            fr[e] = f2bfs(M[(q * 8 + e) * 32 + nh * 16 + lr]);
        size_t idx = (size_t)(isB ? 4096 : 0) + ((size_t)grp * 2 + nh) * 64 + tid;
        ((bf16x8*)wf)[idx] = fr;
    }
}

// ---- main fused kernel: 16 rows per block, 4 waves -------------------------
// zt logical (c,k,r) at byte (c*1024 + k*32 + r*2) ^ ((c&15)<<3)   [bf16]
__global__ __launch_bounds__(256) void bfly_mfma(
    const float* __restrict__ x,
    const short* __restrict__ wf1,
    const short* __restrict__ wf2,
    float* __restrict__ out)
{
    __shared__ char zt[32 * 1024];
    const int tid = threadIdx.x;
    const int w = tid >> 6;
    const int l = tid & 63;
    const int q = l >> 4, lr = l & 15;
    const int row0 = blockIdx.x * ROWS_PER_TILE;

    const f32x4 zacc = {0.f, 0.f, 0.f, 0.f};

    // ---- layer 1: wave w owns g in [w*8, w*8+8) ----
    const float* xrow = x + (size_t)(row0 + lr) * DIM;   // A row = lane&15
    #pragma unroll
    for (int gi = 0; gi < 8; ++gi) {
        const int g = w * 8 + gi;
        const f32x4* xp = (const f32x4*)(xrow + g * 32 + q * 8);
        f32x4 xa = __builtin_nontemporal_load(xp);
        f32x4 xb = __builtin_nontemporal_load(xp + 1);
        bf16x8 af;
        af[0] = f2bfs(xa[0]); af[1] = f2bfs(xa[1]);
        af[2] = f2bfs(xa[2]); af[3] = f2bfs(xa[3]);
        af[4] = f2bfs(xb[0]); af[5] = f2bfs(xb[1]);
        af[6] = f2bfs(xb[2]); af[7] = f2bfs(xb[3]);
        bf16x8 b0 = ((const bf16x8*)wf1)[(g * 2 + 0) * 64 + l];
        bf16x8 b1 = ((const bf16x8*)wf1)[(g * 2 + 1) * 64 + l];
        f32x4 c0 = __builtin_amdgcn_mfma_f32_16x16x32_bf16(af, b0, zacc, 0, 0, 0);
        f32x4 c1 = __builtin_amdgcn_mfma_f32_16x16x32_bf16(af, b1, zacc, 0, 0, 0);
        #pragma unroll
        for (int nh = 0; nh < 2; ++nh) {
            f32x4 cc = nh ? c1 : c0;
            int c = nh * 16 + lr;                 // z column within group = zt 'c'
            unsigned lo = f2bfbits(cc[0]) | (f2bfbits(cc[1]) << 16);
            unsigned hi = f2bfbits(cc[2]) | (f2bfbits(cc[3]) << 16);
            // rows r = q*4+0..3 -> bytes r*2 = q*8..q*8+7 (one b64)
            int byteoff = (c * 1024 + g * 32 + q * 8) ^ ((c & 15) << 3);
            u32x2 pk = {lo, hi};
            *(u32x2*)(zt + byteoff) = pk;
        }
    }
    __syncthreads();

    // ---- layer 2: wave w owns h in [w*8, w*8+8) ----
    f32x4 o[2][8];
    #pragma unroll
    for (int hh = 0; hh < 8; ++hh) {
        const int h = w * 8 + hh;
        bf16x8 a2;
        #pragma unroll
        for (int e = 0; e < 8; ++e) {
            int byteoff = (h * 1024 + (q * 8 + e) * 32 + lr * 2) ^ ((h & 15) << 3);
            union { unsigned short u; short s; } cv;
            cv.u = *(const unsigned short*)(zt + byteoff);
            a2[e] = cv.s;
        }
        bf16x8 b0 = ((const bf16x8*)wf2)[(h * 2 + 0) * 64 + l];
        bf16x8 b1 = ((const bf16x8*)wf2)[(h * 2 + 1) * 64 + l];
        o[0][hh] = __builtin_amdgcn_mfma_f32_16x16x32_bf16(a2, b0, zacc, 0, 0, 0);
        o[1][hh] = __builtin_amdgcn_mfma_f32_16x16x32_bf16(a2, b1, zacc, 0, 0, 0);
    }

    // ---- stores: lane writes 32B contiguous per (nh,i); waves tile 128B ----
    #pragma unroll
    for (int nh = 0; nh < 2; ++nh) {
        #pragma unroll
        for (int i = 0; i < 4; ++i) {
            f32x4 v0 = { o[nh][0][i], o[nh][1][i], o[nh][2][i], o[nh][3][i] };
            f32x4 v1 = { o[nh][4][i], o[nh][5][i], o[nh][6][i], o[nh][7][i] };
            float* dst = out + (size_t)(row0 + q * 4 + i) * DIM
                       + (nh * 16 + lr) * 32 + w * 8;
            *(f32x4*)dst = v0;
            *((f32x4*)dst + 1) = v1;
        }
    }
}

// ---- fallback (ws too small): r6-style unpacked shuffle butterfly ----------
__global__ __launch_bounds__(256) void butterfly_fallback(
    const float* __restrict__ x, const float* __restrict__ Ws,
    float* __restrict__ out, int rows)
{
    const int lane = threadIdx.x & 63;
    const int wave = threadIdx.x >> 6;
    const int row0 = (blockIdx.x * 4 + wave) * 2;
    const float4* __restrict__ Wm = (const float4*)Ws;
    float d[2][16];
    #pragma unroll
    for (int r = 0; r < 2; ++r) {
        int row = row0 + r;
        if (row < rows) {
            const f32x4* src = (const f32x4*)(x + (size_t)row * DIM);
            #pragma unroll
            for (int qq = 0; qq < 4; ++qq) {
                f32x4 v = src[qq * 64 + lane];
                d[r][qq*4+0]=v[0]; d[r][qq*4+1]=v[1]; d[r][qq*4+2]=v[2]; d[r][qq*4+3]=v[3];
            }
        } else { for (int e = 0; e < 16; ++e) d[r][e] = 0.f; }
    }
    #pragma unroll
    for (int qq = 0; qq < 4; ++qq) {
        int base = qq*128 + lane*2;
        float4 m0 = Wm[base], m1 = Wm[base+1];
        #pragma unroll
        for (int r = 0; r < 2; ++r) {
            int e = qq*4; float u,v;
            u=d[r][e+0]; v=d[r][e+1]; d[r][e+0]=u*m0.x+v*m0.z; d[r][e+1]=u*m0.y+v*m0.w;
            u=d[r][e+2]; v=d[r][e+3]; d[r][e+2]=u*m1.x+v*m1.z; d[r][e+3]=u*m1.y+v*m1.w;
        }
    }
    #pragma unroll
    for (int qq = 0; qq < 4; ++qq) {
        int base = 512 + qq*128 + lane*2;
        float4 m0 = Wm[base], m1 = Wm[base+1];
        #pragma unroll
        for (int r = 0; r < 2; ++r) {
            int e = qq*4; float u,v;
            u=d[r][e+0]; v=d[r][e+2]; d[r][e+0]=u*m0.x+v*m0.z; d[r][e+2]=u*m0.y+v*m0.w;
            u=d[r][e+1]; v=d[r][e+3]; d[r][e+1]=u*m1.x+v*m1.z; d[r][e+3]=u*m1.y+v*m1.w;
        }
    }
    #pragma unroll
    for (int i = 2; i < 8; ++i) {
        const int m = 1 << (i - 2);
        #pragma unroll
        for (int qq = 0; qq < 4; ++qq) {
            const int a = (lane >> (i - 2)) & 1;
            int P0 = (((qq*64 + lane) >> (i-1)) << i) | ((lane & (m-1)) << 2);
            int base = i*512 + P0;
            float4 M0 = Wm[base+0], M1 = Wm[base+1], M2 = Wm[base+2], M3 = Wm[base+3];
            float wA0 = a ? M0.w : M0.x, wB0 = a ? M0.y : M0.z;
            float wA1 = a ? M1.w : M1.x, wB1 = a ? M1.y : M1.z;
            float wA2 = a ? M2.w : M2.x, wB2 = a ? M2.y : M2.z;
            float wA3 = a ? M3.w : M3.x, wB3 = a ? M3.y : M3.z;
            #pragma unroll
            for (int r = 0; r < 2; ++r) {
                int e = qq*4;
                float o0=__shfl_xor(d[r][e+0],m), o1=__shfl_xor(d[r][e+1],m);
                float o2=__shfl_xor(d[r][e+2],m), o3=__shfl_xor(d[r][e+3],m);
                d[r][e+0]=d[r][e+0]*wA0+o0*wB0; d[r][e+1]=d[r][e+1]*wA1+o1*wB1;
                d[r][e+2]=d[r][e+2]*wA2+o2*wB2; d[r][e+3]=d[r][e+3]*wA3+o3*wB3;
            }
        }
    }
    #pragma unroll
    for (int qp = 0; qp < 2; ++qp) {
        int base = 8*512 + qp*256 + lane*4;
        float4 M0 = Wm[base+0], M1 = Wm[base+1], M2 = Wm[base+2], M3 = Wm[base+3];
        #pragma unroll
        for (int r = 0; r < 2; ++r) {
            int eu=(2*qp)*4, ev=(2*qp+1)*4; float u,v;
            u=d[r][eu+0]; v=d[r][ev+0]; d[r][eu+0]=u*M0.x+v*M0.z; d[r][ev+0]=u*M0.y+v*M0.w;
            u=d[r][eu+1]; v=d[r][ev+1]; d[r][eu+1]=u*M1.x+v*M1.z; d[r][ev+1]=u*M1.y+v*M1.w;
            u=d[r][eu+2]; v=d[r][ev+2]; d[r][eu+2]=u*M2.x+v*M2.z; d[r][ev+2]=u*M2.y+v*M2.w;
            u=d[r][eu+3]; v=d[r][ev+3]; d[r][eu+3]=u*M3.x+v*M3.z; d[r][ev+3]=u*M3.y+v*M3.w;
        }
    }
    #pragma unroll
    for (int qp = 0; qp < 2; ++qp) {
        int base = 9*512 + qp*256 + lane*4;
        float4 M0 = Wm[base+0], M1 = Wm[base+1], M2 = Wm[base+2], M3 = Wm[base+3];
        #pragma unroll
        for (int r = 0; r < 2; ++r) {
            int eu=qp*4, ev=(qp+2)*4; float u,v;
            u=d[r][eu+0]; v=d[r][ev+0]; d[r][eu+0]=u*M0.x+v*M0.z; d[r][ev+0]=u*M0.y+v*M0.w;
            u=d[r][eu+1]; v=d[r][ev+1]; d[r][eu+1]=u*M1.x+v*M1.z; d[r][ev+1]=u*M1.y+v*M1.w;
            u=d[r][eu+2]; v=d[r][ev+2]; d[r][eu+2]=u*M2.x+v*M2.z; d[r][ev+2]=u*M2.y+v*M2.w;
            u=d[r][eu+3]; v=d[r][ev+3]; d[r][eu+3]=u*M3.x+v*M3.z; d[r][ev+3]=u*M3.y+v*M3.w;
        }
    }
    #pragma unroll
    for (int r = 0; r < 2; ++r) {
        int row = row0 + r;
        if (row < rows) {
            f32x4* dst = (f32x4*)(out + (size_t)row * DIM);
            #pragma unroll
            for (int qq = 0; qq < 4; ++qq) {
                f32x4 v = { d[r][qq*4+0], d[r][qq*4+1], d[r][qq*4+2], d[r][qq*4+3] };
                dst[qq * 64 + lane] = v;
            }
        }
    }
}

extern "C" void kernel_launch(void* const* d_in, const int* in_sizes, int n_in,
                              void* d_out, int out_size, void* d_ws, size_t ws_size,
                              hipStream_t stream) {
    const float* x  = (const float*)d_in[0];
    const float* Ws = (const float*)d_in[1];
    float* out = (float*)d_out;
    int rows = in_sizes[0] / DIM;

    if (ws_size >= (size_t)WF_BYTES && (rows % ROWS_PER_TILE) == 0) {
        short* wf1 = (short*)d_ws;
        short* wf2 = (short*)d_ws + 32768;   // +64KB
        compose_pack<<<64, 64, 0, stream>>>(Ws, (short*)d_ws);
        bfly_mfma<<<rows / ROWS_PER_TILE, 256, 0, stream>>>(x, wf1, wf2, out);
    } else {
        int grid = (rows + 7) / 8;
        butterfly_fallback<<<grid, 256, 0, stream>>>(x, Ws, out, rows);
    }
}

// Round 12
// 46.527 us; speedup vs baseline: 1.3008x; 1.3008x over previous
//
#include <hip/hip_runtime.h>

#define DIM 1024
#define ROWS_PER_TILE 16

typedef float  f32x4  __attribute__((ext_vector_type(4)));
typedef short  bf16x8 __attribute__((ext_vector_type(8)));
typedef unsigned int u32x2 __attribute__((ext_vector_type(2)));
typedef unsigned int u32x4 __attribute__((ext_vector_type(4)));

#define WF_BYTES (2 * 32 * 2 * 64 * 16)   // wf1 (64KB) + wf2 (64KB) in d_ws

// ===========================================================================
// y = x * M. Stages 0-4 mix bits 0-4 -> blockdiag over contiguous 32-groups g:
//   z[r][g*32+n] = sum_k x[r][g*32+k] * A_g[k][n]
// Stages 5-9 mix bits 5-9 -> blockdiag over stride-32 groups t:
//   y[r][n*32+t] = sum_k z[r][k*32+t] * B_t[k][n]
// zt layout (layer1 -> layer2): z as [c=bits4:0][g=bits9:5][r], byte
//   (c*1024 + g*32 + r*2) ^ ((c&15)<<3)  -- verified r11 (passed).
// Layer 2 uses SWAPPED operands: mfma(A=wf2 frag, B=z frag) so each lane holds
// y[row=lr][8 consecutive cols] -> bf16-staged in LDS -> coalesced f32 stores.
// (r11 evidence: direct strided stores caused 2x WRITE_SIZE -> HBM RMW.)
// ===========================================================================

__device__ __forceinline__ short f2bfs(float f) {
    union { __bf16 b; short s; } c; c.b = (__bf16)f; return c.s;
}
__device__ __forceinline__ unsigned f2bfbits(float f) {
    union { __bf16 b; unsigned short u; } c; c.b = (__bf16)f; return (unsigned)c.u;
}
__device__ __forceinline__ float bfbits2f(unsigned bits16shifted) {
    union { unsigned u; float f; } c; c.u = bits16shifted; return c.f;
}

// ---- compose A_g / B_t from Ws; emit fragments (identical for both layers):
// lane supplies M[k=(tid>>4)*8+e][ nh*16 + (tid&15) ]  (k x non-k layout).
__global__ __launch_bounds__(64) void compose_pack(const float* __restrict__ Ws,
                                                   short* __restrict__ wf) {
    __shared__ float M[32 * 32];
    const int b = blockIdx.x;
    const int tid = threadIdx.x;
    const bool isB = b >= 32;
    const int grp = isB ? b - 32 : b;

    for (int s = tid; s < 1024; s += 64) M[s] = ((s >> 5) == (s & 31)) ? 1.f : 0.f;
    __syncthreads();

    for (int il = 0; il < 5; ++il) {
        #pragma unroll
        for (int s = 0; s < 8; ++s) {
            int task = tid + s * 64;        // 512 tasks: pl(16) x row(32), disjoint
            int pl = task >> 5;
            int r  = task & 31;
            int lo = ((pl >> il) << (il + 1)) | (pl & ((1 << il) - 1));
            int hi = lo + (1 << il);
            int wi = isB ? ((5 + il) * 512 + pl * 32 + grp)
                         : (il * 512 + grp * 16 + pl);
            const float* W = Ws + (size_t)wi * 4;
            float w00 = W[0], w01 = W[1], w10 = W[2], w11 = W[3];
            float u = M[r * 32 + lo], v = M[r * 32 + hi];
            M[r * 32 + lo] = u * w00 + v * w10;
            M[r * 32 + hi] = u * w01 + v * w11;
        }
        __syncthreads();
    }

    const int q = tid >> 4, lr = tid & 15;
    #pragma unroll
    for (int nh = 0; nh < 2; ++nh) {
        bf16x8 fr;
        #pragma unroll
        for (int e = 0; e < 8; ++e)
            fr[e] = f2bfs(M[(q * 8 + e) * 32 + nh * 16 + lr]);
        size_t idx = (size_t)(isB ? 4096 : 0) + ((size_t)grp * 2 + nh) * 64 + tid;
        ((bf16x8*)wf)[idx] = fr;
    }
}

// ---- main fused kernel: 16 rows per block, 4 waves -------------------------
__global__ __launch_bounds__(256) void bfly_mfma(
    const float* __restrict__ x,
    const short* __restrict__ wf1,
    const short* __restrict__ wf2,
    float* __restrict__ out)
{
    __shared__ char zt[32 * 1024];   // layer1->2 transpose, then y bf16 staging
    const int tid = threadIdx.x;
    const int w = tid >> 6;
    const int l = tid & 63;
    const int q = l >> 4, lr = l & 15;
    const int row0 = blockIdx.x * ROWS_PER_TILE;

    const f32x4 zacc = {0.f, 0.f, 0.f, 0.f};

    // ---- layer 1: wave w owns g in [w*8, w*8+8); A rows = x rows (m = lr) ----
    const float* xrow = x + (size_t)(row0 + lr) * DIM;
    #pragma unroll
    for (int gi = 0; gi < 8; ++gi) {
        const int g = w * 8 + gi;
        const f32x4* xp = (const f32x4*)(xrow + g * 32 + q * 8);
        f32x4 xa = __builtin_nontemporal_load(xp);
        f32x4 xb = __builtin_nontemporal_load(xp + 1);
        bf16x8 af;
        af[0] = f2bfs(xa[0]); af[1] = f2bfs(xa[1]);
        af[2] = f2bfs(xa[2]); af[3] = f2bfs(xa[3]);
        af[4] = f2bfs(xb[0]); af[5] = f2bfs(xb[1]);
        af[6] = f2bfs(xb[2]); af[7] = f2bfs(xb[3]);
        bf16x8 b0 = ((const bf16x8*)wf1)[(g * 2 + 0) * 64 + l];
        bf16x8 b1 = ((const bf16x8*)wf1)[(g * 2 + 1) * 64 + l];
        f32x4 c0 = __builtin_amdgcn_mfma_f32_16x16x32_bf16(af, b0, zacc, 0, 0, 0);
        f32x4 c1 = __builtin_amdgcn_mfma_f32_16x16x32_bf16(af, b1, zacc, 0, 0, 0);
        #pragma unroll
        for (int nh = 0; nh < 2; ++nh) {
            f32x4 cc = nh ? c1 : c0;
            int c = nh * 16 + lr;                 // z col within group
            unsigned lo = f2bfbits(cc[0]) | (f2bfbits(cc[1]) << 16);
            unsigned hi = f2bfbits(cc[2]) | (f2bfbits(cc[3]) << 16);
            int byteoff = (c * 1024 + g * 32 + q * 8) ^ ((c & 15) << 3);
            u32x2 pk = {lo, hi};
            *(u32x2*)(zt + byteoff) = pk;
        }
    }
    __syncthreads();

    // ---- layer 2 (swapped): A = wf2 frag (m = output col idx), B = z frag ----
    // z frag: B[k=q*8+e][n=lr] = z[row=lr][k*32+t], t = h.
    f32x4 o[2][8];
    #pragma unroll
    for (int hh = 0; hh < 8; ++hh) {
        const int h = w * 8 + hh;
        bf16x8 a2;
        #pragma unroll
        for (int e = 0; e < 8; ++e) {
            int byteoff = (h * 1024 + (q * 8 + e) * 32 + lr * 2) ^ ((h & 15) << 3);
            union { unsigned short u; short s; } cv;
            cv.u = *(const unsigned short*)(zt + byteoff);
            a2[e] = cv.s;
        }
        bf16x8 b0 = ((const bf16x8*)wf2)[(h * 2 + 0) * 64 + l];
        bf16x8 b1 = ((const bf16x8*)wf2)[(h * 2 + 1) * 64 + l];
        o[0][hh] = __builtin_amdgcn_mfma_f32_16x16x32_bf16(b0, a2, zacc, 0, 0, 0);
        o[1][hh] = __builtin_amdgcn_mfma_f32_16x16x32_bf16(b1, a2, zacc, 0, 0, 0);
    }
    __syncthreads();   // all zt reads done before reuse as y-staging

    // ---- stage y into LDS as bf16 [row][col], swizzled 16B units ----
    // lane holds y[row=lr][col=(nh*16+q*4+i)*32 + w*8 + hh]
    #pragma unroll
    for (int nh = 0; nh < 2; ++nh) {
        #pragma unroll
        for (int i = 0; i < 4; ++i) {
            unsigned p0 = f2bfbits(o[nh][0][i]) | (f2bfbits(o[nh][1][i]) << 16);
            unsigned p1 = f2bfbits(o[nh][2][i]) | (f2bfbits(o[nh][3][i]) << 16);
            unsigned p2 = f2bfbits(o[nh][4][i]) | (f2bfbits(o[nh][5][i]) << 16);
            unsigned p3 = f2bfbits(o[nh][6][i]) | (f2bfbits(o[nh][7][i]) << 16);
            int colb = (nh * 16 + q * 4 + i) * 32 + w * 8;
            int u = lr * 128 + (colb >> 3);       // 16-B unit index
            u ^= (u >> 7) & 7;                    // bank-balance (involution)
            u32x4 pk = {p0, p1, p2, p3};
            *(u32x4*)(zt + u * 16) = pk;
        }
    }
    __syncthreads();

    // ---- coalesced f32 stores: thread t -> row t>>4, 8x (16B LDS -> 32B out) ----
    const int trow = tid >> 4;
    const int tcb  = tid & 15;
    float* orow = out + (size_t)(row0 + trow) * DIM;
    #pragma unroll
    for (int j = 0; j < 8; ++j) {
        int ucol = j * 16 + tcb;                  // 0..127
        int u = trow * 128 + ucol;
        u ^= (u >> 7) & 7;
        u32x4 pk = *(const u32x4*)(zt + u * 16);
        f32x4 v0, v1;
        v0[0] = bfbits2f(pk[0] << 16); v0[1] = bfbits2f(pk[0] & 0xffff0000u);
        v0[2] = bfbits2f(pk[1] << 16); v0[3] = bfbits2f(pk[1] & 0xffff0000u);
        v1[0] = bfbits2f(pk[2] << 16); v1[1] = bfbits2f(pk[2] & 0xffff0000u);
        v1[2] = bfbits2f(pk[3] << 16); v1[3] = bfbits2f(pk[3] & 0xffff0000u);
        float* dst = orow + ucol * 8;
        *(f32x4*)dst = v0;
        *((f32x4*)dst + 1) = v1;
    }
}

// ---- fallback (ws too small / odd rows): r6-style shuffle butterfly --------
__global__ __launch_bounds__(256) void butterfly_fallback(
    const float* __restrict__ x, const float* __restrict__ Ws,
    float* __restrict__ out, int rows)
{
    const int lane = threadIdx.x & 63;
    const int wave = threadIdx.x >> 6;
    const int row0 = (blockIdx.x * 4 + wave) * 2;
    const float4* __restrict__ Wm = (const float4*)Ws;
    float d[2][16];
    #pragma unroll
    for (int r = 0; r < 2; ++r) {
        int row = row0 + r;
        if (row < rows) {
            const f32x4* src = (const f32x4*)(x + (size_t)row * DIM);
            #pragma unroll
            for (int qq = 0; qq < 4; ++qq) {
                f32x4 v = src[qq * 64 + lane];
                d[r][qq*4+0]=v[0]; d[r][qq*4+1]=v[1]; d[r][qq*4+2]=v[2]; d[r][qq*4+3]=v[3];
            }
        } else { for (int e = 0; e < 16; ++e) d[r][e] = 0.f; }
    }
    #pragma unroll
    for (int qq = 0; qq < 4; ++qq) {
        int base = qq*128 + lane*2;
        float4 m0 = Wm[base], m1 = Wm[base+1];
        #pragma unroll
        for (int r = 0; r < 2; ++r) {
            int e = qq*4; float u,v;
            u=d[r][e+0]; v=d[r][e+1]; d[r][e+0]=u*m0.x+v*m0.z; d[r][e+1]=u*m0.y+v*m0.w;
            u=d[r][e+2]; v=d[r][e+3]; d[r][e+2]=u*m1.x+v*m1.z; d[r][e+3]=u*m1.y+v*m1.w;
        }
    }
    #pragma unroll
    for (int qq = 0; qq < 4; ++qq) {
        int base = 512 + qq*128 + lane*2;
        float4 m0 = Wm[base], m1 = Wm[base+1];
        #pragma unroll
        for (int r = 0; r < 2; ++r) {
            int e = qq*4; float u,v;
            u=d[r][e+0]; v=d[r][e+2]; d[r][e+0]=u*m0.x+v*m0.z; d[r][e+2]=u*m0.y+v*m0.w;
            u=d[r][e+1]; v=d[r][e+3]; d[r][e+1]=u*m1.x+v*m1.z; d[r][e+3]=u*m1.y+v*m1.w;
        }
    }
    #pragma unroll
    for (int i = 2; i < 8; ++i) {
        const int m = 1 << (i - 2);
        #pragma unroll
        for (int qq = 0; qq < 4; ++qq) {
            const int a = (lane >> (i - 2)) & 1;
            int P0 = (((qq*64 + lane) >> (i-1)) << i) | ((lane & (m-1)) << 2);
            int base = i*512 + P0;
            float4 M0 = Wm[base+0], M1 = Wm[base+1], M2 = Wm[base+2], M3 = Wm[base+3];
            float wA0 = a ? M0.w : M0.x, wB0 = a ? M0.y : M0.z;
            float wA1 = a ? M1.w : M1.x, wB1 = a ? M1.y : M1.z;
            float wA2 = a ? M2.w : M2.x, wB2 = a ? M2.y : M2.z;
            float wA3 = a ? M3.w : M3.x, wB3 = a ? M3.y : M3.z;
            #pragma unroll
            for (int r = 0; r < 2; ++r) {
                int e = qq*4;
                float o0=__shfl_xor(d[r][e+0],m), o1=__shfl_xor(d[r][e+1],m);
                float o2=__shfl_xor(d[r][e+2],m), o3=__shfl_xor(d[r][e+3],m);
                d[r][e+0]=d[r][e+0]*wA0+o0*wB0; d[r][e+1]=d[r][e+1]*wA1+o1*wB1;
                d[r][e+2]=d[r][e+2]*wA2+o2*wB2; d[r][e+3]=d[r][e+3]*wA3+o3*wB3;
            }
        }
    }
    #pragma unroll
    for (int qp = 0; qp < 2; ++qp) {
        int base = 8*512 + qp*256 + lane*4;
        float4 M0 = Wm[base+0], M1 = Wm[base+1], M2 = Wm[base+2], M3 = Wm[base+3];
        #pragma unroll
        for (int r = 0; r < 2; ++r) {
            int eu=(2*qp)*4, ev=(2*qp+1)*4; float u,v;
            u=d[r][eu+0]; v=d[r][ev+0]; d[r][eu+0]=u*M0.x+v*M0.z; d[r][ev+0]=u*M0.y+v*M0.w;
            u=d[r][eu+1]; v=d[r][ev+1]; d[r][eu+1]=u*M1.x+v*M1.z; d[r][ev+1]=u*M1.y+v*M1.w;
            u=d[r][eu+2]; v=d[r][ev+2]; d[r][eu+2]=u*M2.x+v*M2.z; d[r][ev+2]=u*M2.y+v*M2.w;
            u=d[r][eu+3]; v=d[r][ev+3]; d[r][eu+3]=u*M3.x+v*M3.z; d[r][ev+3]=u*M3.y+v*M3.w;
        }
    }
    #pragma unroll
    for (int qp = 0; qp < 2; ++qp) {
        int base = 9*512 + qp*256 + lane*4;
        float4 M0 = Wm[base+0], M1 = Wm[base+1], M2 = Wm[base+2], M3 = Wm[base+3];
        #pragma unroll
        for (int r = 0; r < 2; ++r) {
            int eu=qp*4, ev=(qp+2)*4; float u,v;
            u=d[r][eu+0]; v=d[r][ev+0]; d[r][eu+0]=u*M0.x+v*M0.z; d[r][ev+0]=u*M0.y+v*M0.w;
            u=d[r][eu+1]; v=d[r][ev+1]; d[r][eu+1]=u*M1.x+v*M1.z; d[r][ev+1]=u*M1.y+v*M1.w;
            u=d[r][eu+2]; v=d[r][ev+2]; d[r][eu+2]=u*M2.x+v*M2.z; d[r][ev+2]=u*M2.y+v*M2.w;
            u=d[r][eu+3]; v=d[r][ev+3]; d[r][eu+3]=u*M3.x+v*M3.z; d[r][ev+3]=u*M3.y+v*M3.w;
        }
    }
    #pragma unroll
    for (int r = 0; r < 2; ++r) {
        int row = row0 + r;
        if (row < rows) {
            f32x4* dst = (f32x4*)(out + (size_t)row * DIM);
            #pragma unroll
            for (int qq = 0; qq < 4; ++qq) {
                f32x4 v = { d[r][qq*4+0], d[r][qq*4+1], d[r][qq*4+2], d[r][qq*4+3] };
                dst[qq * 64 + lane] = v;
            }
        }
    }
}

extern "C" void kernel_launch(void* const* d_in, const int* in_sizes, int n_in,
                              void* d_out, int out_size, void* d_ws, size_t ws_size,
                              hipStream_t stream) {
    const float* x  = (const float*)d_in[0];
    const float* Ws = (const float*)d_in[1];
    float* out = (float*)d_out;
    int rows = in_sizes[0] / DIM;

    if (ws_size >= (size_t)WF_BYTES && (rows % ROWS_PER_TILE) == 0) {
        short* wf1 = (short*)d_ws;
        short* wf2 = (short*)d_ws + 32768;   // +64KB
        compose_pack<<<64, 64, 0, stream>>>(Ws, (short*)d_ws);
        bfly_mfma<<<rows / ROWS_PER_TILE, 256, 0, stream>>>(x, wf1, wf2, out);
    } else {
        int grid = (rows + 7) / 8;
        butterfly_fallback<<<grid, 256, 0, stream>>>(x, Ws, out, rows);
    }
}